// Round 3
// baseline (326.629 us; speedup 1.0000x reference)
//
#include <hip/hip_runtime.h>
#include <math.h>
#include <stdint.h>

#define HH 480
#define WW 640
#define HW (HH*WW)
#define KK 512
#define DD 256
#define KP1 513
#define NSLOT 16
#define NBX 40
#define NBY 30
#define SLOTS_PER_IMG (NBX*NBY*NSLOT)   /* 19200 */
#define SVCAP 4096
#define GRIDB 16
#define NORM_F (-6.9314718055994531f)   /* -log(1024) */
#define LOGK_F (6.2383246250395077f)    /* log(512) */
#define MU0 (1.0f/1024.0f)
#define MU1 (0.5f)

// ---------------- ws layout (bytes) ----------------
#define OFF_OFFS   0u          /* 1024 int */
#define OFF_GHIST  4096u       /* 2 * 1024 int */
#define OFF_FLAGS  12288u      /* arrive[16] + release, pad to 256 */
#define OFF_SCORE  16384u      /* 2 * HW f32 ; Z aliases (score dead after nms) */
#define OFF_Z      16384u
#define OFF_SMOOTH 2473984u    /* 2 * HW f32 */
#define OFF_CAND   4931584u    /* 2 * 19200 u64 = 307200 */
#define OFF_KIDX   5238784u    /* 2 * 512 int */
#define OFF_DESC   5242880u    /* 2 * 512 * 256 f32 */
#define OFF_SBUF   6291456u    /* 2 * 512 f32 */
#define OFF_PCOL   6295552u    /* 2 * 16 * 513 f32 = 65664 */

// ---------------------------------------------------------------------------
// MT19937(42) -> numpy RandomState.randint(-8,9,(256,4)) replication.
// ---------------------------------------------------------------------------
__global__ __launch_bounds__(256) void gen_offsets_kernel(int* __restrict__ offs) {
  __shared__ unsigned int st[624], nx[624];
  __shared__ unsigned int outv[4992];
  __shared__ int csum[256];
  const int t = threadIdx.x;
  if (t == 0) {
    unsigned int x = 42u;
    st[0] = x;
    for (int i = 1; i < 624; ++i) { x = 1812433253u*(x ^ (x >> 30)) + (unsigned)i; st[i] = x; }
  }
  __syncthreads();
  for (int blk = 0; blk < 8; ++blk) {
    for (int i = t; i < 227; i += 256) {
      unsigned int y = (st[i] & 0x80000000u) | (st[i+1] & 0x7fffffffu);
      nx[i] = st[i+397] ^ (y >> 1) ^ ((y & 1u) ? 2567483615u : 0u);
    }
    __syncthreads();
    for (int i = 227 + t; i < 454; i += 256) {
      unsigned int y = (st[i] & 0x80000000u) | (st[i+1] & 0x7fffffffu);
      nx[i] = nx[i-227] ^ (y >> 1) ^ ((y & 1u) ? 2567483615u : 0u);
    }
    __syncthreads();
    for (int i = 454 + t; i < 624; i += 256) {
      unsigned int y;
      if (i < 623) y = (st[i] & 0x80000000u) | (st[i+1] & 0x7fffffffu);
      else         y = (st[623] & 0x80000000u) | (nx[0] & 0x7fffffffu);
      nx[i] = nx[i-227] ^ (y >> 1) ^ ((y & 1u) ? 2567483615u : 0u);
    }
    __syncthreads();
    for (int i = t; i < 624; i += 256) {
      unsigned int y = nx[i];
      y ^= y >> 11;
      y ^= (y << 7)  & 2636928640u;
      y ^= (y << 15) & 4022730752u;
      y ^= y >> 18;
      outv[blk*624 + i] = y;
      st[i] = nx[i];
    }
    __syncthreads();
  }
  const int base = t * 20;
  int cnt = 0;
  for (int e = 0; e < 20; ++e) {
    int i = base + e;
    if (i < 4992 && (outv[i] & 31u) <= 16u) cnt++;
  }
  csum[t] = cnt;
  __syncthreads();
  if (t == 0) {
    int run = 0;
    for (int i = 0; i < 256; ++i) { int tmp = csum[i]; csum[i] = run; run += tmp; }
  }
  __syncthreads();
  int pos = csum[t];
  for (int e = 0; e < 20; ++e) {
    int i = base + e;
    if (i < 4992) {
      unsigned int mv = outv[i] & 31u;
      if (mv <= 16u) { if (pos < 1024) offs[pos] = (int)mv - 8; pos++; }
    }
  }
}

// ---------------------------------------------------------------------------
// Fused detector: Sobel -> products -> 3x3 box -> min-eig score, plus 5x5 smooth.
// ---------------------------------------------------------------------------
__global__ __launch_bounds__(256) void detector_kernel(const float* __restrict__ img0,
    const float* __restrict__ img1, float* __restrict__ score, float* __restrict__ smooth) {
  __shared__ float tile[20][20];
  __shared__ float pxx[18][18], pyy[18][18], pxy[18][18];
  const int imgI = blockIdx.z;
  const float* img = imgI ? img1 : img0;
  const int bx0 = blockIdx.x * 16, by0 = blockIdx.y * 16;
  const int tx = threadIdx.x, ty = threadIdx.y;
  const int lt = ty * 16 + tx;
  for (int p = lt; p < 400; p += 256) {
    int r = p / 20, c = p % 20;
    int gy = by0 - 2 + r, gx = bx0 - 2 + c;
    float v = 0.f;
    if (gy >= 0 && gy < HH && gx >= 0 && gx < WW) v = img[gy*WW + gx];
    tile[r][c] = v;
  }
  __syncthreads();
  for (int p = lt; p < 324; p += 256) {
    int r = p / 18, c = p % 18;
    int gy = by0 - 1 + r, gx = bx0 - 1 + c;
    float vxx = 0.f, vyy = 0.f, vxy = 0.f;
    if (gy >= 0 && gy < HH && gx >= 0 && gx < WW) {
      float t00 = tile[r][c],   t01 = tile[r][c+1],   t02 = tile[r][c+2];
      float t10 = tile[r+1][c],                        t12 = tile[r+1][c+2];
      float t20 = tile[r+2][c], t21 = tile[r+2][c+1], t22 = tile[r+2][c+2];
      float ix = t00*(-1.f) + t02*1.f + t10*(-2.f) + t12*2.f + t20*(-1.f) + t22*1.f;
      float iy = t00*(-1.f) + t01*(-2.f) + t02*(-1.f) + t20*1.f + t21*2.f + t22*1.f;
      vxx = ix*ix; vyy = iy*iy; vxy = ix*iy;
    }
    pxx[r][c] = vxx; pyy[r][c] = vyy; pxy[r][c] = vxy;
  }
  __syncthreads();
  const float c9 = 1.f/9.f, c25 = 1.f/25.f;
  float sxx = 0.f, syy = 0.f, sxy = 0.f;
  for (int r = 0; r < 3; ++r)
    for (int c = 0; c < 3; ++c) {
      sxx += pxx[ty+r][tx+c] * c9;
      syy += pyy[ty+r][tx+c] * c9;
      sxy += pxy[ty+r][tx+c] * c9;
    }
  float tdif = sxx - syy;
  float disc = tdif*tdif + 4.f*(sxy*sxy) + 1e-12f;
  float sc = 0.5f * ((sxx + syy) - sqrtf(disc));
  float sm = 0.f;
  for (int r = 0; r < 5; ++r)
    for (int c = 0; c < 5; ++c)
      sm += tile[ty+r][tx+c] * c25;
  int y = by0 + ty, x = bx0 + tx;
  score [imgI*HW + y*WW + x] = sc;
  smooth[imgI*HW + y*WW + x] = sm;
}

// ---------------------------------------------------------------------------
// 7x7 NMS -> per-block slot compaction + 1024-bin global histogram (top 10
// bits of score). No returning atomics on hot path; hist adds fire-and-forget.
// ---------------------------------------------------------------------------
__global__ __launch_bounds__(256) void nms_kernel(const float* __restrict__ score,
    unsigned long long* __restrict__ cand, int* __restrict__ ghist) {
  __shared__ float t[22][22];
  __shared__ int wsum[4];
  __shared__ int wbase[4];
  const int imgI = blockIdx.z;
  const float* s = score + imgI*HW;
  const int bx0 = blockIdx.x*16, by0 = blockIdx.y*16;
  const int tx = threadIdx.x, ty = threadIdx.y, lt = ty*16+tx;
  for (int p = lt; p < 484; p += 256) {
    int r = p/22, c = p%22;
    int gy = by0-3+r, gx = bx0-3+c;
    t[r][c] = (gy >= 0 && gy < HH && gx >= 0 && gx < WW) ? s[gy*WW+gx] : -INFINITY;
  }
  __syncthreads();
  float cv = t[ty+3][tx+3];
  float m = -INFINITY;
  for (int r = 0; r < 7; ++r)
    for (int c = 0; c < 7; ++c)
      m = fmaxf(m, t[ty+r][tx+c]);
  bool pred = (cv >= m && cv > 0.f);
  unsigned long long mask = __ballot(pred);
  int lane = lt & 63, wid = lt >> 6;
  if (lane == 0) wsum[wid] = __popcll(mask);
  __syncthreads();
  if (lt == 0) {
    int s0 = wsum[0], s1 = wsum[1], s2 = wsum[2], s3 = wsum[3];
    wbase[0] = 0; wbase[1] = s0; wbase[2] = s0+s1; wbase[3] = s0+s1+s2;
    wsum[0] = s0+s1+s2+s3;
  }
  __syncthreads();
  const int total = wsum[0];
  const size_t slotBase = (size_t)imgI*SLOTS_PER_IMG + (size_t)(blockIdx.y*NBX + blockIdx.x)*NSLOT;
  if (pred) {
    int pos = wbase[wid] + __popcll(mask & ((1ull << lane) - 1ull));
    if (pos < NSLOT) {
      int idx = (by0+ty)*WW + (bx0+tx);
      unsigned int ub = __float_as_uint(cv) | 0x80000000u;
      cand[slotBase + pos] = ((unsigned long long)ub << 32) | (unsigned int)(~idx);
      atomicAdd(&ghist[imgI*1024 + (int)(ub >> 22)], 1);
    }
  }
  if (lt >= total && lt < NSLOT) cand[slotBase + lt] = 0ull;
}

// ---------------------------------------------------------------------------
// Top-512 sorted select: suffix-scan global hist -> threshold bin b1 ->
// compact survivors (~600) to LDS -> O(n^2) rank-by-count (broadcast reads,
// unique keys -> unique ranks -> deterministic) -> emit kpts/kidx.
// ---------------------------------------------------------------------------
__global__ __launch_bounds__(1024) void select2_kernel(const unsigned long long* __restrict__ cand,
    const int* __restrict__ ghist, float* __restrict__ kptsOut, int* __restrict__ kidx) {
  __shared__ unsigned long long sk[SVCAP];
  __shared__ unsigned long long sorted[KK];
  __shared__ int hist[1024];
  __shared__ int sB1, sCount;
  const int imgI = blockIdx.x, t = threadIdx.x;
  const unsigned long long* cd = cand + (size_t)imgI*SLOTS_PER_IMG;
  hist[t] = ghist[imgI*1024 + t];
  if (t == 0) { sB1 = 0; sCount = 0; }
  if (t < KK) sorted[t] = 0ull;
  __syncthreads();
  for (int d = 1; d < 1024; d <<= 1) {            // suffix scan
    int vv = hist[t] + ((t + d < 1024) ? hist[t + d] : 0);
    __syncthreads();
    hist[t] = vv;
    __syncthreads();
  }
  if (hist[t] >= KK) atomicMax(&sB1, t);
  __syncthreads();
  const int b1 = sB1;
  for (int i = t; i < SLOTS_PER_IMG; i += 1024) {
    unsigned long long k = cd[i];
    if (k && (int)(k >> 54) >= b1) {
      int pos = atomicAdd(&sCount, 1);
      if (pos < SVCAP) sk[pos] = k;
    }
  }
  __syncthreads();
  int n = sCount; if (n > SVCAP) n = SVCAP;
  for (int i = t; i < n; i += 1024) {
    unsigned long long key = sk[i];
    int r = 0;
    for (int m = 0; m < n; ++m) r += (sk[m] > key) ? 1 : 0;
    if (r < KK) sorted[r] = key;
  }
  __syncthreads();
  if (t < KK) {
    unsigned long long key = sorted[t];
    float y = -1.f, x = -1.f;
    int id = -1;
    if (key != 0ull) {
      id = (int)(~(unsigned int)(key & 0xFFFFFFFFull));
      y = (float)(id / WW);
      x = (float)(id % WW);
    }
    kptsOut[imgI*2*KK + 2*t]     = y;
    kptsOut[imgI*2*KK + 2*t + 1] = x;
    kidx[imgI*KK + t] = id;
  }
}

// ---------------------------------------------------------------------------
// Per-keypoint BAD descriptor (edge-clamped gathers on smooth) + L2 norm + s
// ---------------------------------------------------------------------------
__global__ __launch_bounds__(256) void desc_kernel(const float* __restrict__ smooth,
    const int* __restrict__ kidx, const int* __restrict__ offs,
    float* __restrict__ desc, float* __restrict__ sbuf) {
  __shared__ float wsum[4];
  const int k = blockIdx.x, imgI = blockIdx.y;
  const int j = threadIdx.x;
  const int id = kidx[imgI*KK + k];
  float val = 0.f;
  if (id >= 0) {
    int y = id / WW, x = id % WW;
    int o0 = offs[4*j], o1 = offs[4*j+1], o2 = offs[4*j+2], o3 = offs[4*j+3];
    const float* sm = smooth + imgI*HW;
    int ya = min(max(y+o0, 0), HH-1), xa = min(max(x+o1, 0), WW-1);
    int yb = min(max(y+o2, 0), HH-1), xb = min(max(x+o3, 0), WW-1);
    val = sm[ya*WW + xa] - sm[yb*WW + xb];
  }
  float ss = val*val;
  for (int off = 32; off; off >>= 1) ss += __shfl_down(ss, off);
  if ((j & 63) == 0) wsum[j >> 6] = ss;
  __syncthreads();
  if (j == 0) wsum[0] = wsum[0] + wsum[1] + wsum[2] + wsum[3];
  __syncthreads();
  float tot = wsum[0];
  float inv = 1.f / (sqrtf(tot) + 1e-12f);
  desc[((size_t)imgI*KK + k)*DD + j] = val * inv;
  if (j == 0) sbuf[imgI*KK + k] = tot * inv * inv;
}

// ---------------------------------------------------------------------------
// Z = -sqrt(clip(s1+s2-2*d1.d2, 1e-12)); dustbins = 1.0 (row-major only)
// ---------------------------------------------------------------------------
__global__ __launch_bounds__(256) void zbuild_kernel(const float* __restrict__ desc,
    const float* __restrict__ sbuf, float* __restrict__ Z) {
  __shared__ float sA[16][260], sB[16][260];
  const int ty = threadIdx.y, tx = threadIdx.x;
  const int i0 = blockIdx.y*16, j0 = blockIdx.x*16;
  const int lt = ty*16 + tx;
  for (int p = lt; p < 16*DD; p += 256) {
    int r = p / DD, c = p % DD;
    sA[r][c] = (i0 + r < KK) ? desc[((size_t)0*KK + i0 + r)*DD + c] : 0.f;
    sB[r][c] = (j0 + r < KK) ? desc[((size_t)1*KK + j0 + r)*DD + c] : 0.f;
  }
  __syncthreads();
  const int i = i0 + ty, j = j0 + tx;
  if (i > KK || j > KK) return;
  if (i < KK && j < KK) {
    float acc = 0.f;
    for (int c = 0; c < DD; ++c) acc += sA[ty][c] * sB[tx][c];
    float d2 = sbuf[0*KK + i] + sbuf[1*KK + j] - 2.f*acc;
    Z[i*KP1 + j] = -sqrtf(fmaxf(d2, 1e-12f));
  } else {
    Z[i*KP1 + j] = 1.0f;
  }
}

// ---------------------------------------------------------------------------
// Cooperative fused Sinkhorn (20 iters, 1 grid barrier each) + probs.
// Math: t_ij = exp(Z_ij + v_j); S_i = sum_j t_ij; u_i = log(mu_i/S_i);
//       P_j = sum_i t_ij * (mu_i/S_i)  [per-block slices, fixed-order sum]
//       v'_j = lognu_j + v_j - log(sum_b P_b,j)      (one barrier per iter)
// Bounded args -> no max-subtraction needed in f32.
// Each block keeps its own full v[513] in LDS; u lives in wave registers.
// ---------------------------------------------------------------------------
__global__ __launch_bounds__(1024) void sinkhorn_kernel(const float* __restrict__ Z,
    float* __restrict__ Pcol, int* __restrict__ flags, float* __restrict__ probs) {
  __shared__ float v[KP1];
  __shared__ float pcolw[GRIDB][KP1];
  const int t = threadIdx.x, b = blockIdx.x;
  const int widx = t >> 6, lane = t & 63;
  const int gw = b*GRIDB + widx;          // global wave id 0..255
  int* arrive  = flags;                    // [GRIDB]
  int* release = flags + GRIDB;
  for (int j = t; j < KP1; j += 1024) v[j] = 0.f;
  __syncthreads();
  const int nrows = (gw == 255) ? 3 : 2;
  int rows[3] = { 2*gw, 2*gw+1, 512 };
  float uval[3] = {0.f, 0.f, 0.f};
  for (int it = 0; it < 20; ++it) {
    float pacc[9];
    #pragma unroll
    for (int e = 0; e < 9; ++e) pacc[e] = 0.f;
    for (int rr = 0; rr < nrows; ++rr) {
      const int r = rows[rr];
      const float* zr = Z + (size_t)r*KP1;
      float tv[9]; float S = 0.f;
      #pragma unroll
      for (int e = 0; e < 8; ++e) {
        int j = lane + 64*e;
        tv[e] = expf(zr[j] + v[j]);
        S += tv[e];
      }
      tv[8] = 0.f;
      if (lane == 0) { tv[8] = expf(zr[512] + v[512]); S += tv[8]; }
      #pragma unroll
      for (int off = 32; off; off >>= 1) S += __shfl_xor(S, off);
      float mu = (r < 512) ? MU0 : MU1;
      float eu = mu / S;
      uval[rr] = logf(eu);                 // = logmu - log(S)
      #pragma unroll
      for (int e = 0; e < 9; ++e) pacc[e] += tv[e] * eu;
    }
    #pragma unroll
    for (int e = 0; e < 8; ++e) pcolw[widx][lane + 64*e] = pacc[e];
    if (lane == 0) pcolw[widx][512] = pacc[8];
    __syncthreads();
    float* pc = Pcol + (size_t)(it & 1)*GRIDB*KP1 + (size_t)b*KP1;
    for (int j = t; j < KP1; j += 1024) {
      float s = 0.f;
      #pragma unroll
      for (int w = 0; w < GRIDB; ++w) s += pcolw[w][j];
      __hip_atomic_store(&pc[j], s, __ATOMIC_RELAXED, __HIP_MEMORY_SCOPE_AGENT);
    }
    // ---- grid barrier (generation = it+1) ----
    __syncthreads();
    const int gen = it + 1;
    if (t == 0) {
      __threadfence();
      __hip_atomic_store(&arrive[b], gen, __ATOMIC_RELEASE, __HIP_MEMORY_SCOPE_AGENT);
    }
    if (b == 0) {
      if (t < GRIDB) {
        while (__hip_atomic_load(&arrive[t], __ATOMIC_ACQUIRE, __HIP_MEMORY_SCOPE_AGENT) < gen) {}
      }
      __syncthreads();
      if (t == 0) __hip_atomic_store(release, gen, __ATOMIC_RELEASE, __HIP_MEMORY_SCOPE_AGENT);
    }
    if (t == 0) {
      while (__hip_atomic_load(release, __ATOMIC_ACQUIRE, __HIP_MEMORY_SCOPE_AGENT) < gen) {}
      __threadfence();
    }
    __syncthreads();
    // ---- v update (every block computes full v from all slices) ----
    const float* pcAll = Pcol + (size_t)(it & 1)*GRIDB*KP1;
    for (int j = t; j < KP1; j += 1024) {
      float s = 0.f;
      #pragma unroll
      for (int w = 0; w < GRIDB; ++w)
        s += __hip_atomic_load(&pcAll[(size_t)w*KP1 + j], __ATOMIC_RELAXED, __HIP_MEMORY_SCOPE_AGENT);
      float lognu = (j < 512) ? NORM_F : (LOGK_F + NORM_F);
      v[j] = lognu + v[j] - logf(s);
    }
    __syncthreads();
  }
  // probs = exp(Z + u + v - norm)
  for (int rr = 0; rr < nrows; ++rr) {
    const int r = rows[rr];
    const float* zr = Z + (size_t)r*KP1;
    float* pr = probs + (size_t)r*KP1;
    const float ur = uval[rr];
    #pragma unroll
    for (int e = 0; e < 8; ++e) {
      int j = lane + 64*e;
      pr[j] = expf(zr[j] + ur + v[j] - NORM_F);
    }
    if (lane == 0) pr[512] = expf(zr[512] + ur + v[512] - NORM_F);
  }
}

extern "C" void kernel_launch(void* const* d_in, const int* in_sizes, int n_in,
                              void* d_out, int out_size, void* d_ws, size_t ws_size,
                              hipStream_t stream) {
  const float* img1 = (const float*)d_in[0];
  const float* img2 = (const float*)d_in[1];
  float* out = (float*)d_out;
  char* ws = (char*)d_ws;

  int*   offs   = (int*)  (ws + OFF_OFFS);
  int*   ghist  = (int*)  (ws + OFF_GHIST);
  int*   flags  = (int*)  (ws + OFF_FLAGS);
  float* score  = (float*)(ws + OFF_SCORE);
  float* smooth = (float*)(ws + OFF_SMOOTH);
  unsigned long long* cand = (unsigned long long*)(ws + OFF_CAND);
  int*   kidx   = (int*)  (ws + OFF_KIDX);
  float* desc   = (float*)(ws + OFF_DESC);
  float* sbuf   = (float*)(ws + OFF_SBUF);
  float* Z      = (float*)(ws + OFF_Z);     // aliases SCORE region
  float* pcol   = (float*)(ws + OFF_PCOL);
  float* probsOut = out + 2*KK*2;

  // zero ghist + flags in one shot (covers [OFF_GHIST, OFF_FLAGS+256))
  hipMemsetAsync(ws + OFF_GHIST, 0, 8192 + 256, stream);

  gen_offsets_kernel<<<1, 256, 0, stream>>>(offs);
  detector_kernel<<<dim3(NBX, NBY, 2), dim3(16, 16), 0, stream>>>(img1, img2, score, smooth);
  nms_kernel<<<dim3(NBX, NBY, 2), dim3(16, 16), 0, stream>>>(score, cand, ghist);
  select2_kernel<<<2, 1024, 0, stream>>>(cand, ghist, out, kidx);
  desc_kernel<<<dim3(KK, 2), 256, 0, stream>>>(smooth, kidx, offs, desc, sbuf);
  zbuild_kernel<<<dim3(33, 33), dim3(16, 16), 0, stream>>>(desc, sbuf, Z);
  void* args[] = { (void*)&Z, (void*)&pcol, (void*)&flags, (void*)&probsOut };
  hipLaunchCooperativeKernel((const void*)sinkhorn_kernel, dim3(GRIDB), dim3(1024),
                             args, 0, stream);
}

// Round 4
// 226.979 us; speedup vs baseline: 1.4390x; 1.4390x over previous
//
#include <hip/hip_runtime.h>
#include <math.h>
#include <stdint.h>

#define HH 480
#define WW 640
#define HW (HH*WW)
#define KK 512
#define DD 256
#define KP1 513
#define NSLOT 16
#define NBX 40
#define NBY 30
#define SLOTS_PER_IMG (NBX*NBY*NSLOT)   /* 19200 */
#define SVCAP 4096
#define SB 32                            /* sinkhorn blocks */
#define NORM_F (-6.9314718055994531f)   /* -log(1024) */
#define LOGK_F (6.2383246250395077f)    /* log(512) */
#define MU0 (1.0f/1024.0f)
#define MU1 (0.5f)

// ---------------- ws layout (bytes) ----------------
#define OFF_GHIST  0u          /* 2 * 1024 int = 8192 */
#define OFF_SCORE  16384u      /* 2 * HW f32 ; Z aliases (score dead after nms) */
#define OFF_Z      16384u      /* 513*513*4 = 1052676 (inside score region) */
#define OFF_SMOOTH 2473984u    /* 2 * HW f32 */
#define OFF_CAND   4931584u    /* 2 * 19200 u64 = 307200 */
#define OFF_KIDX   5238784u    /* 2 * 512 int */
#define OFF_DESC   5242880u    /* 2 * 512 * 256 f32 */
#define OFF_SBUF   6291456u    /* 2 * 512 f32 */
#define OFF_PCA    6295552u    /* SB * 513 f32 = 65664 */
#define OFF_PCB    6361216u    /* SB * 513 f32 = 65664 */
#define OFF_VA     6426880u    /* 513 f32 (pad 2304) */
#define OFF_VB     6429184u
#define OFF_U      6431488u

// ---------------------------------------------------------------------------
// BAD pair offsets: numpy RandomState(42).randint(-8,9,(256,4)) replicated at
// COMPILE TIME (MT19937 init + twist + temper + masked rejection, &31, <=16).
// Same algorithm that passed on-device in rounds 1-3; now a constant table.
// ---------------------------------------------------------------------------
struct OffsTab { int v[1024]; };
static constexpr OffsTab make_offsets() {
  OffsTab o{};
  unsigned st[624] = {};
  st[0] = 42u;
  for (int i = 1; i < 624; ++i)
    st[i] = 1812433253u*(st[i-1] ^ (st[i-1] >> 30)) + (unsigned)i;
  int idx = 624, got = 0;
  while (got < 1024) {
    if (idx == 624) {
      for (int i = 0; i < 624; ++i) {
        unsigned y = (st[i] & 0x80000000u) | (st[(i+1)%624] & 0x7fffffffu);
        st[i] = st[(i+397)%624] ^ (y >> 1) ^ ((y & 1u) ? 2567483615u : 0u);
      }
      idx = 0;
    }
    unsigned y = st[idx++];
    y ^= y >> 11;
    y ^= (y << 7)  & 2636928640u;
    y ^= (y << 15) & 4022730752u;
    y ^= y >> 18;
    unsigned mv = y & 31u;
    if (mv <= 16u) { o.v[got] = (int)mv - 8; ++got; }
  }
  return o;
}
__device__ __constant__ OffsTab OFFS = make_offsets();

// ---------------------------------------------------------------------------
// Fused detector: Sobel -> products -> 3x3 box -> min-eig score, plus 5x5 smooth.
// ---------------------------------------------------------------------------
__global__ __launch_bounds__(256) void detector_kernel(const float* __restrict__ img0,
    const float* __restrict__ img1, float* __restrict__ score, float* __restrict__ smooth) {
  __shared__ float tile[20][20];
  __shared__ float pxx[18][18], pyy[18][18], pxy[18][18];
  const int imgI = blockIdx.z;
  const float* img = imgI ? img1 : img0;
  const int bx0 = blockIdx.x * 16, by0 = blockIdx.y * 16;
  const int tx = threadIdx.x, ty = threadIdx.y;
  const int lt = ty * 16 + tx;
  for (int p = lt; p < 400; p += 256) {
    int r = p / 20, c = p % 20;
    int gy = by0 - 2 + r, gx = bx0 - 2 + c;
    float v = 0.f;
    if (gy >= 0 && gy < HH && gx >= 0 && gx < WW) v = img[gy*WW + gx];
    tile[r][c] = v;
  }
  __syncthreads();
  for (int p = lt; p < 324; p += 256) {
    int r = p / 18, c = p % 18;
    int gy = by0 - 1 + r, gx = bx0 - 1 + c;
    float vxx = 0.f, vyy = 0.f, vxy = 0.f;
    if (gy >= 0 && gy < HH && gx >= 0 && gx < WW) {
      float t00 = tile[r][c],   t01 = tile[r][c+1],   t02 = tile[r][c+2];
      float t10 = tile[r+1][c],                        t12 = tile[r+1][c+2];
      float t20 = tile[r+2][c], t21 = tile[r+2][c+1], t22 = tile[r+2][c+2];
      float ix = t00*(-1.f) + t02*1.f + t10*(-2.f) + t12*2.f + t20*(-1.f) + t22*1.f;
      float iy = t00*(-1.f) + t01*(-2.f) + t02*(-1.f) + t20*1.f + t21*2.f + t22*1.f;
      vxx = ix*ix; vyy = iy*iy; vxy = ix*iy;
    }
    pxx[r][c] = vxx; pyy[r][c] = vyy; pxy[r][c] = vxy;
  }
  __syncthreads();
  const float c9 = 1.f/9.f, c25 = 1.f/25.f;
  float sxx = 0.f, syy = 0.f, sxy = 0.f;
  for (int r = 0; r < 3; ++r)
    for (int c = 0; c < 3; ++c) {
      sxx += pxx[ty+r][tx+c] * c9;
      syy += pyy[ty+r][tx+c] * c9;
      sxy += pxy[ty+r][tx+c] * c9;
    }
  float tdif = sxx - syy;
  float disc = tdif*tdif + 4.f*(sxy*sxy) + 1e-12f;
  float sc = 0.5f * ((sxx + syy) - sqrtf(disc));
  float sm = 0.f;
  for (int r = 0; r < 5; ++r)
    for (int c = 0; c < 5; ++c)
      sm += tile[ty+r][tx+c] * c25;
  int y = by0 + ty, x = bx0 + tx;
  score [imgI*HW + y*WW + x] = sc;
  smooth[imgI*HW + y*WW + x] = sm;
}

// ---------------------------------------------------------------------------
// 7x7 NMS -> per-block slot compaction + 1024-bin global histogram (ub>>22).
// ---------------------------------------------------------------------------
__global__ __launch_bounds__(256) void nms_kernel(const float* __restrict__ score,
    unsigned long long* __restrict__ cand, int* __restrict__ ghist) {
  __shared__ float t[22][22];
  __shared__ int wsum[4];
  __shared__ int wbase[4];
  const int imgI = blockIdx.z;
  const float* s = score + imgI*HW;
  const int bx0 = blockIdx.x*16, by0 = blockIdx.y*16;
  const int tx = threadIdx.x, ty = threadIdx.y, lt = ty*16+tx;
  for (int p = lt; p < 484; p += 256) {
    int r = p/22, c = p%22;
    int gy = by0-3+r, gx = bx0-3+c;
    t[r][c] = (gy >= 0 && gy < HH && gx >= 0 && gx < WW) ? s[gy*WW+gx] : -INFINITY;
  }
  __syncthreads();
  float cv = t[ty+3][tx+3];
  float m = -INFINITY;
  for (int r = 0; r < 7; ++r)
    for (int c = 0; c < 7; ++c)
      m = fmaxf(m, t[ty+r][tx+c]);
  bool pred = (cv >= m && cv > 0.f);
  unsigned long long mask = __ballot(pred);
  int lane = lt & 63, wid = lt >> 6;
  if (lane == 0) wsum[wid] = __popcll(mask);
  __syncthreads();
  if (lt == 0) {
    int s0 = wsum[0], s1 = wsum[1], s2 = wsum[2], s3 = wsum[3];
    wbase[0] = 0; wbase[1] = s0; wbase[2] = s0+s1; wbase[3] = s0+s1+s2;
    wsum[0] = s0+s1+s2+s3;
  }
  __syncthreads();
  const int total = wsum[0];
  const size_t slotBase = (size_t)imgI*SLOTS_PER_IMG + (size_t)(blockIdx.y*NBX + blockIdx.x)*NSLOT;
  if (pred) {
    int pos = wbase[wid] + __popcll(mask & ((1ull << lane) - 1ull));
    if (pos < NSLOT) {
      int idx = (by0+ty)*WW + (bx0+tx);
      unsigned int ub = __float_as_uint(cv) | 0x80000000u;
      cand[slotBase + pos] = ((unsigned long long)ub << 32) | (unsigned int)(~idx);
      atomicAdd(&ghist[imgI*1024 + (int)(ub >> 22)], 1);
    }
  }
  if (lt >= total && lt < NSLOT) cand[slotBase + lt] = 0ull;
}

// ---------------------------------------------------------------------------
// Top-512 sorted select: level-1 (precomputed ghist, 10 bits) + level-2
// (LDS hist, next 10 mantissa bits) threshold -> survivors ~520 ->
// O(n^2) rank-by-count (unique keys -> deterministic) -> kpts/kidx.
// ---------------------------------------------------------------------------
__global__ __launch_bounds__(1024) void select2_kernel(const unsigned long long* __restrict__ cand,
    const int* __restrict__ ghist, float* __restrict__ kptsOut, int* __restrict__ kidx) {
  __shared__ unsigned long long sk[SVCAP];
  __shared__ unsigned long long sorted[KK];
  __shared__ int hist[1024];
  __shared__ int sB1, sB2, sNeed, sCount;
  const int imgI = blockIdx.x, t = threadIdx.x;
  const unsigned long long* cd = cand + (size_t)imgI*SLOTS_PER_IMG;
  hist[t] = ghist[imgI*1024 + t];
  if (t == 0) { sB1 = -1; sB2 = 0; sCount = 0; }
  if (t < KK) sorted[t] = 0ull;
  __syncthreads();
  for (int d = 1; d < 1024; d <<= 1) {            // suffix scan
    int vv = hist[t] + ((t + d < 1024) ? hist[t + d] : 0);
    __syncthreads();
    hist[t] = vv;
    __syncthreads();
  }
  if (hist[t] >= KK) atomicMax(&sB1, t);
  __syncthreads();
  const int b1 = sB1;
  if (t == 0 && b1 >= 0) sNeed = KK - ((b1 < 1023) ? hist[b1 + 1] : 0);
  __syncthreads();
  int b2 = 0;
  if (b1 >= 0) {
    hist[t] = 0;
    __syncthreads();
    for (int i = t; i < SLOTS_PER_IMG; i += 1024) {
      unsigned long long k = cd[i];
      if (k && (int)(k >> 54) == b1) atomicAdd(&hist[(int)(k >> 44) & 1023], 1);
    }
    __syncthreads();
    for (int d = 1; d < 1024; d <<= 1) {
      int vv = hist[t] + ((t + d < 1024) ? hist[t + d] : 0);
      __syncthreads();
      hist[t] = vv;
      __syncthreads();
    }
    if (hist[t] >= sNeed) atomicMax(&sB2, t);
    __syncthreads();
    b2 = sB2;
  }
  for (int i = t; i < SLOTS_PER_IMG; i += 1024) {
    unsigned long long k = cd[i];
    if (k) {
      int bin1 = (int)(k >> 54);
      if (bin1 > b1 || (bin1 == b1 && ((int)(k >> 44) & 1023) >= b2)) {
        int pos = atomicAdd(&sCount, 1);
        if (pos < SVCAP) sk[pos] = k;
      }
    }
  }
  __syncthreads();
  int n = sCount; if (n > SVCAP) n = SVCAP;
  for (int i = t; i < n; i += 1024) {
    unsigned long long key = sk[i];
    int r = 0;
    for (int m = 0; m < n; ++m) r += (sk[m] > key) ? 1 : 0;
    if (r < KK) sorted[r] = key;
  }
  __syncthreads();
  if (t < KK) {
    unsigned long long key = sorted[t];
    float y = -1.f, x = -1.f;
    int id = -1;
    if (key != 0ull) {
      id = (int)(~(unsigned int)(key & 0xFFFFFFFFull));
      y = (float)(id / WW);
      x = (float)(id % WW);
    }
    kptsOut[imgI*2*KK + 2*t]     = y;
    kptsOut[imgI*2*KK + 2*t + 1] = x;
    kidx[imgI*KK + t] = id;
  }
}

// ---------------------------------------------------------------------------
// Per-keypoint BAD descriptor (edge-clamped gathers on smooth) + L2 norm + s
// ---------------------------------------------------------------------------
__global__ __launch_bounds__(256) void desc_kernel(const float* __restrict__ smooth,
    const int* __restrict__ kidx, float* __restrict__ desc, float* __restrict__ sbuf) {
  __shared__ float wsum[4];
  const int k = blockIdx.x, imgI = blockIdx.y;
  const int j = threadIdx.x;
  const int id = kidx[imgI*KK + k];
  float val = 0.f;
  if (id >= 0) {
    int y = id / WW, x = id % WW;
    int o0 = OFFS.v[4*j], o1 = OFFS.v[4*j+1], o2 = OFFS.v[4*j+2], o3 = OFFS.v[4*j+3];
    const float* sm = smooth + imgI*HW;
    int ya = min(max(y+o0, 0), HH-1), xa = min(max(x+o1, 0), WW-1);
    int yb = min(max(y+o2, 0), HH-1), xb = min(max(x+o3, 0), WW-1);
    val = sm[ya*WW + xa] - sm[yb*WW + xb];
  }
  float ss = val*val;
  for (int off = 32; off; off >>= 1) ss += __shfl_down(ss, off);
  if ((j & 63) == 0) wsum[j >> 6] = ss;
  __syncthreads();
  if (j == 0) wsum[0] = wsum[0] + wsum[1] + wsum[2] + wsum[3];
  __syncthreads();
  float tot = wsum[0];
  float inv = 1.f / (sqrtf(tot) + 1e-12f);
  desc[((size_t)imgI*KK + k)*DD + j] = val * inv;
  if (j == 0) sbuf[imgI*KK + k] = tot * inv * inv;
}

// ---------------------------------------------------------------------------
// Z = -sqrt(clip(s1+s2-2*d1.d2, 1e-12)); dustbins = 1.0
// ---------------------------------------------------------------------------
__global__ __launch_bounds__(256) void zbuild_kernel(const float* __restrict__ desc,
    const float* __restrict__ sbuf, float* __restrict__ Z) {
  __shared__ float sA[16][260], sB[16][260];
  const int ty = threadIdx.y, tx = threadIdx.x;
  const int i0 = blockIdx.y*16, j0 = blockIdx.x*16;
  const int lt = ty*16 + tx;
  for (int p = lt; p < 16*DD; p += 256) {
    int r = p / DD, c = p % DD;
    sA[r][c] = (i0 + r < KK) ? desc[((size_t)0*KK + i0 + r)*DD + c] : 0.f;
    sB[r][c] = (j0 + r < KK) ? desc[((size_t)1*KK + j0 + r)*DD + c] : 0.f;
  }
  __syncthreads();
  const int i = i0 + ty, j = j0 + tx;
  if (i > KK || j > KK) return;
  if (i < KK && j < KK) {
    float acc = 0.f;
    for (int c = 0; c < DD; ++c) acc += sA[ty][c] * sB[tx][c];
    float d2 = sbuf[0*KK + i] + sbuf[1*KK + j] - 2.f*acc;
    Z[i*KP1 + j] = -sqrtf(fmaxf(d2, 1e-12f));
  } else {
    Z[i*KP1 + j] = 1.0f;
  }
}

// ---------------------------------------------------------------------------
// Split-phase Sinkhorn step: launch-boundary IS the grid barrier.
// mode 0 (first):  v=0; row pass -> PcolOut slices, u, vOut(=0)
// mode 1 (mid):    v' = lognu + vIn - log(sum_w PcolIn[w]); row pass -> PcolOut
// mode 2 (final):  v' as above; probs = exp(Z + u + v' - norm)
// Each block: 16 waves, wave w owns row b*16+w; wave 511 also owns row 512.
// All sums fixed-order -> deterministic.
// ---------------------------------------------------------------------------
__global__ __launch_bounds__(1024) void sink_step_kernel(const float* __restrict__ Z,
    const float* __restrict__ PcolIn, float* __restrict__ PcolOut,
    const float* __restrict__ vIn, float* __restrict__ vOut,
    float* __restrict__ uBuf, float* __restrict__ probs, int mode) {
  __shared__ float v[KP1];
  __shared__ float pcolw[16][KP1];
  const int t = threadIdx.x, b = blockIdx.x;
  const int widx = t >> 6, lane = t & 63;
  const int gw = b*16 + widx;   // 0..511
  if (mode == 0) {
    for (int j = t; j < KP1; j += 1024) v[j] = 0.f;
  } else {
    for (int j = t; j < KP1; j += 1024) {
      float s = 0.f;
      #pragma unroll
      for (int w = 0; w < SB; ++w) s += PcolIn[w*KP1 + j];
      float lognu = (j < KK) ? NORM_F : (LOGK_F + NORM_F);
      v[j] = lognu + vIn[j] - logf(s);
    }
  }
  __syncthreads();
  if (mode == 2) {
    const int nrows = (gw == 511) ? 2 : 1;
    for (int rr = 0; rr < nrows; ++rr) {
      const int r = rr ? 512 : gw;
      const float* zr = Z + (size_t)r*KP1;
      float* pr = probs + (size_t)r*KP1;
      const float ur = uBuf[r];
      #pragma unroll
      for (int e = 0; e < 8; ++e) {
        int j = lane + 64*e;
        pr[j] = expf(zr[j] + ur + v[j] - NORM_F);
      }
      if (lane == 0) pr[512] = expf(zr[512] + ur + v[512] - NORM_F);
    }
    return;
  }
  // row pass: S_i, u_i, scaled-row accumulation into per-wave column slice
  float pacc[9];
  #pragma unroll
  for (int e = 0; e < 9; ++e) pacc[e] = 0.f;
  const int nrows = (gw == 511) ? 2 : 1;
  for (int rr = 0; rr < nrows; ++rr) {
    const int r = rr ? 512 : gw;
    const float* zr = Z + (size_t)r*KP1;
    float tv[9]; float S = 0.f;
    #pragma unroll
    for (int e = 0; e < 8; ++e) {
      int j = lane + 64*e;
      tv[e] = expf(zr[j] + v[j]);
      S += tv[e];
    }
    tv[8] = 0.f;
    if (lane == 0) { tv[8] = expf(zr[512] + v[512]); S += tv[8]; }
    #pragma unroll
    for (int off = 32; off; off >>= 1) S += __shfl_xor(S, off);
    float mu = (r < 512) ? MU0 : MU1;
    float eu = mu / S;
    if (lane == 0) uBuf[r] = logf(eu);
    #pragma unroll
    for (int e = 0; e < 9; ++e) pacc[e] += tv[e] * eu;
  }
  #pragma unroll
  for (int e = 0; e < 8; ++e) pcolw[widx][lane + 64*e] = pacc[e];
  if (lane == 0) pcolw[widx][512] = pacc[8];
  __syncthreads();
  float* pc = PcolOut + (size_t)b*KP1;
  for (int j = t; j < KP1; j += 1024) {
    float s = 0.f;
    #pragma unroll
    for (int w = 0; w < 16; ++w) s += pcolw[w][j];
    pc[j] = s;
  }
  if (b == 0) {
    for (int j = t; j < KP1; j += 1024) vOut[j] = v[j];
  }
}

extern "C" void kernel_launch(void* const* d_in, const int* in_sizes, int n_in,
                              void* d_out, int out_size, void* d_ws, size_t ws_size,
                              hipStream_t stream) {
  const float* img1 = (const float*)d_in[0];
  const float* img2 = (const float*)d_in[1];
  float* out = (float*)d_out;
  char* ws = (char*)d_ws;

  int*   ghist  = (int*)  (ws + OFF_GHIST);
  float* score  = (float*)(ws + OFF_SCORE);
  float* smooth = (float*)(ws + OFF_SMOOTH);
  unsigned long long* cand = (unsigned long long*)(ws + OFF_CAND);
  int*   kidx   = (int*)  (ws + OFF_KIDX);
  float* desc   = (float*)(ws + OFF_DESC);
  float* sbuf   = (float*)(ws + OFF_SBUF);
  float* Z      = (float*)(ws + OFF_Z);     // aliases SCORE region
  float* pcA    = (float*)(ws + OFF_PCA);
  float* pcB    = (float*)(ws + OFF_PCB);
  float* vA     = (float*)(ws + OFF_VA);
  float* vB     = (float*)(ws + OFF_VB);
  float* uBuf   = (float*)(ws + OFF_U);
  float* probsOut = out + 2*KK*2;

  hipMemsetAsync(ws + OFF_GHIST, 0, 8192, stream);

  detector_kernel<<<dim3(NBX, NBY, 2), dim3(16, 16), 0, stream>>>(img1, img2, score, smooth);
  nms_kernel<<<dim3(NBX, NBY, 2), dim3(16, 16), 0, stream>>>(score, cand, ghist);
  select2_kernel<<<2, 1024, 0, stream>>>(cand, ghist, out, kidx);
  desc_kernel<<<dim3(KK, 2), 256, 0, stream>>>(smooth, kidx, desc, sbuf);
  zbuild_kernel<<<dim3(33, 33), dim3(16, 16), 0, stream>>>(desc, sbuf, Z);

  // L0: v=0, row pass -> pcA (vOut=vA holds zeros)
  sink_step_kernel<<<SB, 1024, 0, stream>>>(Z, pcB, pcA, vB, vA, uBuf, probsOut, 0);
  // L1..L19: v-update + row pass, ping-pong
  int ping = 0;  // 0: latest Pcol in pcA / latest v in vA
  for (int it = 1; it < 20; ++it) {
    float* pin  = ping ? pcB : pcA;
    float* pout = ping ? pcA : pcB;
    float* vin  = ping ? vB  : vA;
    float* vout = ping ? vA  : vB;
    sink_step_kernel<<<SB, 1024, 0, stream>>>(Z, pin, pout, vin, vout, uBuf, probsOut, 1);
    ping ^= 1;
  }
  // L20: final v-update + probs
  {
    float* pin = ping ? pcB : pcA;
    float* vin = ping ? vB  : vA;
    sink_step_kernel<<<SB, 1024, 0, stream>>>(Z, pin, pcA /*unused*/, vin, vA /*unused-safe*/, uBuf, probsOut, 2);
  }
}

// Round 5
// 166.917 us; speedup vs baseline: 1.9568x; 1.3598x over previous
//
#include <hip/hip_runtime.h>
#include <math.h>
#include <stdint.h>

#define HH 480
#define WW 640
#define HW (HH*WW)
#define KK 512
#define DD 256
#define KP1 513
#define NSLOT 16
#define NBX 40
#define NBY 30
#define SLOTS_PER_IMG (NBX*NBY*NSLOT)   /* 19200 */
#define SVCAP 4096
#define SB 32                            /* sinkhorn blocks */
#define NORM_F (-6.9314718055994531f)   /* -log(1024) */
#define LOGK_F (6.2383246250395077f)    /* log(512) */
#define MU0 (1.0f/1024.0f)
#define MU1 (0.5f)

// ---------------- ws layout (bytes) ----------------
#define OFF_Z      16384u      /* 513*513*4 = 1052676 */
#define OFF_SMOOTH 2473984u    /* 2 * HW f32 */
#define OFF_CAND   4931584u    /* 2 * 19200 u64 = 307200 */
#define OFF_KIDX   5238784u    /* 2 * 512 int */
#define OFF_DESC   5242880u    /* 2 * 512 * 256 f32 */
#define OFF_SBUF   6291456u    /* 2 * 512 f32 */
#define OFF_PCA    6295552u    /* SB * 513 f32 = 65664 */
#define OFF_PCB    6361216u    /* SB * 513 f32 = 65664 */
#define OFF_VA     6426880u    /* 513 f32 */
#define OFF_VB     6429184u
#define OFF_U      6431488u

// ---------------------------------------------------------------------------
// BAD pair offsets: numpy RandomState(42).randint(-8,9,(256,4)) replicated at
// COMPILE TIME (MT19937 init + twist + temper + masked rejection, &31, <=16).
// ---------------------------------------------------------------------------
struct OffsTab { int v[1024]; };
static constexpr OffsTab make_offsets() {
  OffsTab o{};
  unsigned st[624] = {};
  st[0] = 42u;
  for (int i = 1; i < 624; ++i)
    st[i] = 1812433253u*(st[i-1] ^ (st[i-1] >> 30)) + (unsigned)i;
  int idx = 624, got = 0;
  while (got < 1024) {
    if (idx == 624) {
      for (int i = 0; i < 624; ++i) {
        unsigned y = (st[i] & 0x80000000u) | (st[(i+1)%624] & 0x7fffffffu);
        st[i] = st[(i+397)%624] ^ (y >> 1) ^ ((y & 1u) ? 2567483615u : 0u);
      }
      idx = 0;
    }
    unsigned y = st[idx++];
    y ^= y >> 11;
    y ^= (y << 7)  & 2636928640u;
    y ^= (y << 15) & 4022730752u;
    y ^= y >> 18;
    unsigned mv = y & 31u;
    if (mv <= 16u) { o.v[got] = (int)mv - 8; ++got; }
  }
  return o;
}
__device__ __constant__ OffsTab OFFS = make_offsets();

// ---------------------------------------------------------------------------
// Fused detector + NMS: per 16x16 output tile, compute score on 22x22 halo
// (products 24x24, image tile 26x26, all in LDS), 5x5 smooth for the center,
// 7x7 NMS in-LDS, ballot-compact winners to per-block slots. NO atomics.
// Score math is per-pixel identical to the split detector (bit-exact).
// ---------------------------------------------------------------------------
__global__ __launch_bounds__(256) void detnms_kernel(const float* __restrict__ img0,
    const float* __restrict__ img1, float* __restrict__ smooth,
    unsigned long long* __restrict__ cand) {
  __shared__ float tile[26][26];
  __shared__ float pxx[24][24], pyy[24][24], pxy[24][24];
  __shared__ float sc[22][22];
  __shared__ int wsum[4], wbase[4];
  const int imgI = blockIdx.z;
  const float* img = imgI ? img1 : img0;
  const int bx0 = blockIdx.x*16, by0 = blockIdx.y*16;
  const int tx = threadIdx.x, ty = threadIdx.y, lt = ty*16+tx;
  for (int p = lt; p < 676; p += 256) {
    int r = p/26, c = p%26;
    int gy = by0-5+r, gx = bx0-5+c;
    tile[r][c] = (gy >= 0 && gy < HH && gx >= 0 && gx < WW) ? img[gy*WW+gx] : 0.f;
  }
  __syncthreads();
  for (int p = lt; p < 576; p += 256) {
    int r = p/24, c = p%24;
    int gy = by0-4+r, gx = bx0-4+c;
    float vxx = 0.f, vyy = 0.f, vxy = 0.f;
    if (gy >= 0 && gy < HH && gx >= 0 && gx < WW) {
      float t00 = tile[r][c],   t01 = tile[r][c+1],   t02 = tile[r][c+2];
      float t10 = tile[r+1][c],                        t12 = tile[r+1][c+2];
      float t20 = tile[r+2][c], t21 = tile[r+2][c+1], t22 = tile[r+2][c+2];
      float ix = t00*(-1.f) + t02*1.f + t10*(-2.f) + t12*2.f + t20*(-1.f) + t22*1.f;
      float iy = t00*(-1.f) + t01*(-2.f) + t02*(-1.f) + t20*1.f + t21*2.f + t22*1.f;
      vxx = ix*ix; vyy = iy*iy; vxy = ix*iy;
    }
    pxx[r][c] = vxx; pyy[r][c] = vyy; pxy[r][c] = vxy;
  }
  __syncthreads();
  const float c9 = 1.f/9.f, c25 = 1.f/25.f;
  // 5x5 smooth for this thread's center pixel (tile offset +3,+3)
  float sm = 0.f;
  for (int r = 0; r < 5; ++r)
    for (int c = 0; c < 5; ++c)
      sm += tile[ty+3+r][tx+3+c] * c25;
  // score on the 22x22 window (-inf outside image)
  for (int p = lt; p < 484; p += 256) {
    int r = p/22, c = p%22;
    int gy = by0-3+r, gx = bx0-3+c;
    float v = -INFINITY;
    if (gy >= 0 && gy < HH && gx >= 0 && gx < WW) {
      float sxx = 0.f, syy = 0.f, sxy = 0.f;
      for (int dr = 0; dr < 3; ++dr)
        for (int dc = 0; dc < 3; ++dc) {
          sxx += pxx[r+dr][c+dc] * c9;
          syy += pyy[r+dr][c+dc] * c9;
          sxy += pxy[r+dr][c+dc] * c9;
        }
      float tdif = sxx - syy;
      v = 0.5f * ((sxx + syy) - sqrtf(tdif*tdif + 4.f*(sxy*sxy) + 1e-12f));
    }
    sc[r][c] = v;
  }
  __syncthreads();
  smooth[imgI*HW + (by0+ty)*WW + (bx0+tx)] = sm;
  float cv = sc[ty+3][tx+3];
  float m = -INFINITY;
  for (int r = 0; r < 7; ++r)
    for (int c = 0; c < 7; ++c)
      m = fmaxf(m, sc[ty+r][tx+c]);
  bool pred = (cv >= m && cv > 0.f);
  unsigned long long mask = __ballot(pred);
  int lane = lt & 63, wid = lt >> 6;
  if (lane == 0) wsum[wid] = __popcll(mask);
  __syncthreads();
  if (lt == 0) {
    int s0 = wsum[0], s1 = wsum[1], s2 = wsum[2], s3 = wsum[3];
    wbase[0] = 0; wbase[1] = s0; wbase[2] = s0+s1; wbase[3] = s0+s1+s2;
    wsum[0] = s0+s1+s2+s3;
  }
  __syncthreads();
  const int total = wsum[0];
  const size_t slotBase = (size_t)imgI*SLOTS_PER_IMG + (size_t)(blockIdx.y*NBX + blockIdx.x)*NSLOT;
  if (pred) {
    int pos = wbase[wid] + __popcll(mask & ((1ull << lane) - 1ull));
    if (pos < NSLOT) {
      int idx = (by0+ty)*WW + (bx0+tx);
      unsigned int ub = __float_as_uint(cv) | 0x80000000u;
      cand[slotBase + pos] = ((unsigned long long)ub << 32) | (unsigned int)(~idx);
    }
  }
  if (lt >= total && lt < NSLOT) cand[slotBase + lt] = 0ull;
}

// ---------------------------------------------------------------------------
// Top-512 sorted select, register-resident: ONE global scan (19 keys/thread in
// VGPRs); level-1 + level-2 LDS histograms with suffix scans -> threshold ->
// compact ~520 survivors -> O(n^2) rank-by-count -> kpts/kidx.
// ---------------------------------------------------------------------------
__global__ __launch_bounds__(1024) void select2_kernel(const unsigned long long* __restrict__ cand,
    float* __restrict__ kptsOut, int* __restrict__ kidx) {
  __shared__ unsigned long long sk[SVCAP];
  __shared__ unsigned long long sorted[KK];
  __shared__ int hist[1024];
  __shared__ int sB1, sB2, sNeed, sCount;
  const int imgI = blockIdx.x, t = threadIdx.x;
  const unsigned long long* cd = cand + (size_t)imgI*SLOTS_PER_IMG;
  unsigned long long kreg[19];
  #pragma unroll
  for (int r = 0; r < 19; ++r) {
    int i = t + r*1024;
    kreg[r] = (i < SLOTS_PER_IMG) ? cd[i] : 0ull;
  }
  hist[t] = 0;
  if (t == 0) { sB1 = -1; sB2 = 0; sCount = 0; }
  if (t < KK) sorted[t] = 0ull;
  __syncthreads();
  #pragma unroll
  for (int r = 0; r < 19; ++r)
    if (kreg[r]) atomicAdd(&hist[(int)(kreg[r] >> 54)], 1);
  __syncthreads();
  for (int d = 1; d < 1024; d <<= 1) {            // suffix scan
    int vv = hist[t] + ((t + d < 1024) ? hist[t + d] : 0);
    __syncthreads();
    hist[t] = vv;
    __syncthreads();
  }
  if (hist[t] >= KK) atomicMax(&sB1, t);
  __syncthreads();
  const int b1 = sB1;
  if (t == 0 && b1 >= 0) sNeed = KK - ((b1 < 1023) ? hist[b1 + 1] : 0);
  __syncthreads();
  int b2 = 0;
  if (b1 >= 0) {
    hist[t] = 0;
    __syncthreads();
    #pragma unroll
    for (int r = 0; r < 19; ++r) {
      unsigned long long k = kreg[r];
      if (k && (int)(k >> 54) == b1) atomicAdd(&hist[(int)(k >> 44) & 1023], 1);
    }
    __syncthreads();
    for (int d = 1; d < 1024; d <<= 1) {
      int vv = hist[t] + ((t + d < 1024) ? hist[t + d] : 0);
      __syncthreads();
      hist[t] = vv;
      __syncthreads();
    }
    if (hist[t] >= sNeed) atomicMax(&sB2, t);
    __syncthreads();
    b2 = sB2;
  }
  #pragma unroll
  for (int r = 0; r < 19; ++r) {
    unsigned long long k = kreg[r];
    if (k) {
      int bin1 = (int)(k >> 54);
      if (bin1 > b1 || (bin1 == b1 && ((int)(k >> 44) & 1023) >= b2)) {
        int pos = atomicAdd(&sCount, 1);
        if (pos < SVCAP) sk[pos] = k;
      }
    }
  }
  __syncthreads();
  int n = sCount; if (n > SVCAP) n = SVCAP;
  for (int i = t; i < n; i += 1024) {
    unsigned long long key = sk[i];
    int rk = 0;
    for (int m = 0; m < n; ++m) rk += (sk[m] > key) ? 1 : 0;
    if (rk < KK) sorted[rk] = key;
  }
  __syncthreads();
  if (t < KK) {
    unsigned long long key = sorted[t];
    float y = -1.f, x = -1.f;
    int id = -1;
    if (key != 0ull) {
      id = (int)(~(unsigned int)(key & 0xFFFFFFFFull));
      y = (float)(id / WW);
      x = (float)(id % WW);
    }
    kptsOut[imgI*2*KK + 2*t]     = y;
    kptsOut[imgI*2*KK + 2*t + 1] = x;
    kidx[imgI*KK + t] = id;
  }
}

// ---------------------------------------------------------------------------
// Per-keypoint BAD descriptor (edge-clamped gathers on smooth) + L2 norm + s
// ---------------------------------------------------------------------------
__global__ __launch_bounds__(256) void desc_kernel(const float* __restrict__ smooth,
    const int* __restrict__ kidx, float* __restrict__ desc, float* __restrict__ sbuf) {
  __shared__ float wsum[4];
  const int k = blockIdx.x, imgI = blockIdx.y;
  const int j = threadIdx.x;
  const int id = kidx[imgI*KK + k];
  float val = 0.f;
  if (id >= 0) {
    int y = id / WW, x = id % WW;
    int o0 = OFFS.v[4*j], o1 = OFFS.v[4*j+1], o2 = OFFS.v[4*j+2], o3 = OFFS.v[4*j+3];
    const float* sm = smooth + imgI*HW;
    int ya = min(max(y+o0, 0), HH-1), xa = min(max(x+o1, 0), WW-1);
    int yb = min(max(y+o2, 0), HH-1), xb = min(max(x+o3, 0), WW-1);
    val = sm[ya*WW + xa] - sm[yb*WW + xb];
  }
  float ss = val*val;
  for (int off = 32; off; off >>= 1) ss += __shfl_down(ss, off);
  if ((j & 63) == 0) wsum[j >> 6] = ss;
  __syncthreads();
  if (j == 0) wsum[0] = wsum[0] + wsum[1] + wsum[2] + wsum[3];
  __syncthreads();
  float tot = wsum[0];
  float inv = 1.f / (sqrtf(tot) + 1e-12f);
  desc[((size_t)imgI*KK + k)*DD + j] = val * inv;
  if (j == 0) sbuf[imgI*KK + k] = tot * inv * inv;
}

// ---------------------------------------------------------------------------
// Z = -sqrt(clip(s1+s2-2*d1.d2, 1e-12)); dustbins = 1.0. float4 LDS dot.
// ---------------------------------------------------------------------------
__global__ __launch_bounds__(256) void zbuild_kernel(const float* __restrict__ desc,
    const float* __restrict__ sbuf, float* __restrict__ Z) {
  __shared__ float sA[16][260], sB[16][260];
  const int ty = threadIdx.y, tx = threadIdx.x;
  const int i0 = blockIdx.y*16, j0 = blockIdx.x*16;
  const int lt = ty*16 + tx;
  for (int p = lt; p < 16*DD; p += 256) {
    int r = p / DD, c = p % DD;
    sA[r][c] = (i0 + r < KK) ? desc[((size_t)0*KK + i0 + r)*DD + c] : 0.f;
    sB[r][c] = (j0 + r < KK) ? desc[((size_t)1*KK + j0 + r)*DD + c] : 0.f;
  }
  __syncthreads();
  const int i = i0 + ty, j = j0 + tx;
  if (i > KK || j > KK) return;
  if (i < KK && j < KK) {
    const float4* pa = (const float4*)&sA[ty][0];
    const float4* pb = (const float4*)&sB[tx][0];
    float acc = 0.f;
    for (int c4 = 0; c4 < DD/4; ++c4) {
      float4 a = pa[c4], b = pb[c4];
      acc += a.x*b.x; acc += a.y*b.y; acc += a.z*b.z; acc += a.w*b.w;
    }
    float d2 = sbuf[0*KK + i] + sbuf[1*KK + j] - 2.f*acc;
    Z[i*KP1 + j] = -sqrtf(fmaxf(d2, 1e-12f));
  } else {
    Z[i*KP1 + j] = 1.0f;
  }
}

// ---------------------------------------------------------------------------
// Split-phase Sinkhorn step: launch-boundary IS the grid barrier.
// mode 0: v=0; row pass -> PcolOut, u.   mode 1: v-update; row pass.
// mode 2: v-update; probs = exp(Z + u + v - norm).
// ---------------------------------------------------------------------------
__global__ __launch_bounds__(1024) void sink_step_kernel(const float* __restrict__ Z,
    const float* __restrict__ PcolIn, float* __restrict__ PcolOut,
    const float* __restrict__ vIn, float* __restrict__ vOut,
    float* __restrict__ uBuf, float* __restrict__ probs, int mode) {
  __shared__ float v[KP1];
  __shared__ float pcolw[16][KP1];
  const int t = threadIdx.x, b = blockIdx.x;
  const int widx = t >> 6, lane = t & 63;
  const int gw = b*16 + widx;   // 0..511
  if (mode == 0) {
    for (int j = t; j < KP1; j += 1024) v[j] = 0.f;
  } else {
    for (int j = t; j < KP1; j += 1024) {
      float s = 0.f;
      #pragma unroll
      for (int w = 0; w < SB; ++w) s += PcolIn[w*KP1 + j];
      float lognu = (j < KK) ? NORM_F : (LOGK_F + NORM_F);
      v[j] = lognu + vIn[j] - logf(s);
    }
  }
  __syncthreads();
  if (mode == 2) {
    const int nrows = (gw == 511) ? 2 : 1;
    for (int rr = 0; rr < nrows; ++rr) {
      const int r = rr ? 512 : gw;
      const float* zr = Z + (size_t)r*KP1;
      float* pr = probs + (size_t)r*KP1;
      const float ur = uBuf[r];
      #pragma unroll
      for (int e = 0; e < 8; ++e) {
        int j = lane + 64*e;
        pr[j] = expf(zr[j] + ur + v[j] - NORM_F);
      }
      if (lane == 0) pr[512] = expf(zr[512] + ur + v[512] - NORM_F);
    }
    return;
  }
  float pacc[9];
  #pragma unroll
  for (int e = 0; e < 9; ++e) pacc[e] = 0.f;
  const int nrows = (gw == 511) ? 2 : 1;
  for (int rr = 0; rr < nrows; ++rr) {
    const int r = rr ? 512 : gw;
    const float* zr = Z + (size_t)r*KP1;
    float tv[9]; float S = 0.f;
    #pragma unroll
    for (int e = 0; e < 8; ++e) {
      int j = lane + 64*e;
      tv[e] = expf(zr[j] + v[j]);
      S += tv[e];
    }
    tv[8] = 0.f;
    if (lane == 0) { tv[8] = expf(zr[512] + v[512]); S += tv[8]; }
    #pragma unroll
    for (int off = 32; off; off >>= 1) S += __shfl_xor(S, off);
    float mu = (r < 512) ? MU0 : MU1;
    float eu = mu / S;
    if (lane == 0) uBuf[r] = logf(eu);
    #pragma unroll
    for (int e = 0; e < 9; ++e) pacc[e] += tv[e] * eu;
  }
  #pragma unroll
  for (int e = 0; e < 8; ++e) pcolw[widx][lane + 64*e] = pacc[e];
  if (lane == 0) pcolw[widx][512] = pacc[8];
  __syncthreads();
  float* pc = PcolOut + (size_t)b*KP1;
  for (int j = t; j < KP1; j += 1024) {
    float s = 0.f;
    #pragma unroll
    for (int w = 0; w < 16; ++w) s += pcolw[w][j];
    pc[j] = s;
  }
  if (b == 0) {
    for (int j = t; j < KP1; j += 1024) vOut[j] = v[j];
  }
}

extern "C" void kernel_launch(void* const* d_in, const int* in_sizes, int n_in,
                              void* d_out, int out_size, void* d_ws, size_t ws_size,
                              hipStream_t stream) {
  const float* img1 = (const float*)d_in[0];
  const float* img2 = (const float*)d_in[1];
  float* out = (float*)d_out;
  char* ws = (char*)d_ws;

  float* smooth = (float*)(ws + OFF_SMOOTH);
  unsigned long long* cand = (unsigned long long*)(ws + OFF_CAND);
  int*   kidx   = (int*)  (ws + OFF_KIDX);
  float* desc   = (float*)(ws + OFF_DESC);
  float* sbuf   = (float*)(ws + OFF_SBUF);
  float* Z      = (float*)(ws + OFF_Z);
  float* pcA    = (float*)(ws + OFF_PCA);
  float* pcB    = (float*)(ws + OFF_PCB);
  float* vA     = (float*)(ws + OFF_VA);
  float* vB     = (float*)(ws + OFF_VB);
  float* uBuf   = (float*)(ws + OFF_U);
  float* probsOut = out + 2*KK*2;

  detnms_kernel<<<dim3(NBX, NBY, 2), dim3(16, 16), 0, stream>>>(img1, img2, smooth, cand);
  select2_kernel<<<2, 1024, 0, stream>>>(cand, out, kidx);
  desc_kernel<<<dim3(KK, 2), 256, 0, stream>>>(smooth, kidx, desc, sbuf);
  zbuild_kernel<<<dim3(33, 33), dim3(16, 16), 0, stream>>>(desc, sbuf, Z);

  sink_step_kernel<<<SB, 1024, 0, stream>>>(Z, pcB, pcA, vB, vA, uBuf, probsOut, 0);
  int ping = 0;
  for (int it = 1; it < 20; ++it) {
    float* pin  = ping ? pcB : pcA;
    float* pout = ping ? pcA : pcB;
    float* vin  = ping ? vB  : vA;
    float* vout = ping ? vA  : vB;
    sink_step_kernel<<<SB, 1024, 0, stream>>>(Z, pin, pout, vin, vout, uBuf, probsOut, 1);
    ping ^= 1;
  }
  {
    float* pin = ping ? pcB : pcA;
    float* vin = ping ? vB  : vA;
    sink_step_kernel<<<SB, 1024, 0, stream>>>(Z, pin, pcA, vin, vA, uBuf, probsOut, 2);
  }
}

// Round 6
// 162.804 us; speedup vs baseline: 2.0063x; 1.0253x over previous
//
#include <hip/hip_runtime.h>
#include <math.h>
#include <stdint.h>

#define HH 480
#define WW 640
#define HW (HH*WW)
#define KK 512
#define DD 256
#define KP1 513
#define NSLOT 16
#define NBX 40
#define NBY 30
#define SLOTS_PER_IMG (NBX*NBY*NSLOT)   /* 19200 */
#define SVN 1024                         /* survivor cap */
#define SB 32                            /* sinkhorn blocks */
#define NORM_F (-6.9314718055994531f)   /* -log(1024) */
#define LOGK_F (6.2383246250395077f)    /* log(512) */
#define MU0 (1.0f/1024.0f)
#define MU1 (0.5f)

// ---------------- ws layout (bytes) ----------------
#define OFF_SURV   0u          /* 2 * 1024 u64 = 16384 */
#define OFF_Z      16384u      /* 512*512*4 = 1048576 (dense, stride 512) */
#define OFF_SMOOTH 2473984u    /* 2 * HW f32 */
#define OFF_CAND   4931584u    /* 2 * 19200 u64 = 307200 */
#define OFF_KIDX   5238784u    /* 2 * 512 int */
#define OFF_DESC   5242880u    /* 2 * 512 * 256 f32 */
#define OFF_SBUF   6291456u    /* 2 * 512 f32 */
#define OFF_PCA    6295552u    /* SB * 513 f32 = 65664 */
#define OFF_PCB    6361216u    /* SB * 513 f32 = 65664 */
#define OFF_VA     6426880u    /* 513 f32 */
#define OFF_VB     6429184u
#define OFF_U      6431488u    /* 513 f32 */
#define OFF_SVCNT  6438912u    /* 2 int */

// ---------------------------------------------------------------------------
// BAD pair offsets: numpy RandomState(42).randint(-8,9,(256,4)) replicated at
// COMPILE TIME (MT19937 init + twist + temper + masked rejection, &31, <=16).
// ---------------------------------------------------------------------------
struct OffsTab { int v[1024]; };
static constexpr OffsTab make_offsets() {
  OffsTab o{};
  unsigned st[624] = {};
  st[0] = 42u;
  for (int i = 1; i < 624; ++i)
    st[i] = 1812433253u*(st[i-1] ^ (st[i-1] >> 30)) + (unsigned)i;
  int idx = 624, got = 0;
  while (got < 1024) {
    if (idx == 624) {
      for (int i = 0; i < 624; ++i) {
        unsigned y = (st[i] & 0x80000000u) | (st[(i+1)%624] & 0x7fffffffu);
        st[i] = st[(i+397)%624] ^ (y >> 1) ^ ((y & 1u) ? 2567483615u : 0u);
      }
      idx = 0;
    }
    unsigned y = st[idx++];
    y ^= y >> 11;
    y ^= (y << 7)  & 2636928640u;
    y ^= (y << 15) & 4022730752u;
    y ^= y >> 18;
    unsigned mv = y & 31u;
    if (mv <= 16u) { o.v[got] = (int)mv - 8; ++got; }
  }
  return o;
}
__device__ __constant__ OffsTab OFFS = make_offsets();

// ---------------------------------------------------------------------------
// Fused detector + NMS. Per 16x16 tile: img 26x26 -> (ix,iy) 24x24 -> score
// 22x22 (exact 9-term order preserved) -> separable 7x7 NMS max (bit-exact)
// -> ballot slot compaction. Smooth via separable 5x5 (continuous path only).
// ---------------------------------------------------------------------------
__global__ __launch_bounds__(256) void detnms_kernel(const float* __restrict__ img0,
    const float* __restrict__ img1, float* __restrict__ smooth,
    unsigned long long* __restrict__ cand) {
  __shared__ float tile[26][26];
  __shared__ float ixA[24][24], iyA[24][24];
  __shared__ float sc[22][22];
  __shared__ float vs[16][26];
  __shared__ float vm[16][22];
  __shared__ int wsum[4], wbase[4];
  const int imgI = blockIdx.z;
  const float* img = imgI ? img1 : img0;
  const int bx0 = blockIdx.x*16, by0 = blockIdx.y*16;
  const int tx = threadIdx.x, ty = threadIdx.y, lt = ty*16+tx;
  for (int p = lt; p < 676; p += 256) {
    int r = p/26, c = p%26;
    int gy = by0-5+r, gx = bx0-5+c;
    tile[r][c] = (gy >= 0 && gy < HH && gx >= 0 && gx < WW) ? img[gy*WW+gx] : 0.f;
  }
  __syncthreads();
  for (int p = lt; p < 576; p += 256) {
    int r = p/24, c = p%24;
    int gy = by0-4+r, gx = bx0-4+c;
    float ix = 0.f, iy = 0.f;
    if (gy >= 0 && gy < HH && gx >= 0 && gx < WW) {
      float t00 = tile[r][c],   t01 = tile[r][c+1],   t02 = tile[r][c+2];
      float t10 = tile[r+1][c],                        t12 = tile[r+1][c+2];
      float t20 = tile[r+2][c], t21 = tile[r+2][c+1], t22 = tile[r+2][c+2];
      ix = t00*(-1.f) + t02*1.f + t10*(-2.f) + t12*2.f + t20*(-1.f) + t22*1.f;
      iy = t00*(-1.f) + t01*(-2.f) + t02*(-1.f) + t20*1.f + t21*2.f + t22*1.f;
    }
    ixA[r][c] = ix; iyA[r][c] = iy;
  }
  __syncthreads();
  const float c9 = 1.f/9.f, c25 = 1.f/25.f;
  // score 22x22: exact same per-term order as split detector (bit-exact)
  for (int p = lt; p < 484; p += 256) {
    int r = p/22, c = p%22;
    int gy = by0-3+r, gx = bx0-3+c;
    float v = -INFINITY;
    if (gy >= 0 && gy < HH && gx >= 0 && gx < WW) {
      float sxx = 0.f, syy = 0.f, sxy = 0.f;
      for (int dr = 0; dr < 3; ++dr)
        for (int dc = 0; dc < 3; ++dc) {
          float jx = ixA[r+dr][c+dc], jy = iyA[r+dr][c+dc];
          float pxxv = jx*jx, pyyv = jy*jy, pxyv = jx*jy;
          sxx += pxxv*c9; syy += pyyv*c9; sxy += pxyv*c9;
        }
      float tdif = sxx - syy;
      v = 0.5f * ((sxx + syy) - sqrtf(tdif*tdif + 4.f*(sxy*sxy) + 1e-12f));
    }
    sc[r][c] = v;
  }
  // vertical 5-sums for smooth
  for (int p = lt; p < 416; p += 256) {
    int i = p/26, c = p%26;
    vs[i][c] = tile[i+3][c] + tile[i+4][c] + tile[i+5][c] + tile[i+6][c] + tile[i+7][c];
  }
  __syncthreads();
  // vertical 7-max for NMS (bit-exact: max is order-insensitive)
  for (int p = lt; p < 352; p += 256) {
    int i = p/22, c = p%22;
    float m = sc[i][c];
    m = fmaxf(m, sc[i+1][c]); m = fmaxf(m, sc[i+2][c]); m = fmaxf(m, sc[i+3][c]);
    m = fmaxf(m, sc[i+4][c]); m = fmaxf(m, sc[i+5][c]); m = fmaxf(m, sc[i+6][c]);
    vm[i][c] = m;
  }
  float sm = (vs[ty][tx+3] + vs[ty][tx+4] + vs[ty][tx+5] + vs[ty][tx+6] + vs[ty][tx+7]) * c25;
  smooth[imgI*HW + (by0+ty)*WW + (bx0+tx)] = sm;
  __syncthreads();
  float cv = sc[ty+3][tx+3];
  float m = vm[ty][tx];
  m = fmaxf(m, vm[ty][tx+1]); m = fmaxf(m, vm[ty][tx+2]); m = fmaxf(m, vm[ty][tx+3]);
  m = fmaxf(m, vm[ty][tx+4]); m = fmaxf(m, vm[ty][tx+5]); m = fmaxf(m, vm[ty][tx+6]);
  bool pred = (cv >= m && cv > 0.f);
  unsigned long long mask = __ballot(pred);
  int lane = lt & 63, wid = lt >> 6;
  if (lane == 0) wsum[wid] = __popcll(mask);
  __syncthreads();
  if (lt == 0) {
    int s0 = wsum[0], s1 = wsum[1], s2 = wsum[2], s3 = wsum[3];
    wbase[0] = 0; wbase[1] = s0; wbase[2] = s0+s1; wbase[3] = s0+s1+s2;
    wsum[0] = s0+s1+s2+s3;
  }
  __syncthreads();
  const int total = wsum[0];
  const size_t slotBase = (size_t)imgI*SLOTS_PER_IMG + (size_t)(blockIdx.y*NBX + blockIdx.x)*NSLOT;
  if (pred) {
    int pos = wbase[wid] + __popcll(mask & ((1ull << lane) - 1ull));
    if (pos < NSLOT) {
      int idx = (by0+ty)*WW + (bx0+tx);
      unsigned int ub = __float_as_uint(cv) | 0x80000000u;
      cand[slotBase + pos] = ((unsigned long long)ub << 32) | (unsigned int)(~idx);
    }
  }
  if (lt >= total && lt < NSLOT) cand[slotBase + lt] = 0ull;
}

// ---------------------------------------------------------------------------
// Threshold + compact: register-resident scan, 2-level (10+10 bit) LDS hist
// with suffix scans -> survivors (~520-600) to global + count. No sorting.
// ---------------------------------------------------------------------------
__global__ __launch_bounds__(1024) void select2a_kernel(const unsigned long long* __restrict__ cand,
    unsigned long long* __restrict__ surv, int* __restrict__ svcnt) {
  __shared__ int hist[1024];
  __shared__ int sB1, sB2, sNeed, sCount;
  const int imgI = blockIdx.x, t = threadIdx.x;
  const unsigned long long* cd = cand + (size_t)imgI*SLOTS_PER_IMG;
  unsigned long long kreg[19];
  #pragma unroll
  for (int r = 0; r < 19; ++r) {
    int i = t + r*1024;
    kreg[r] = (i < SLOTS_PER_IMG) ? cd[i] : 0ull;
  }
  hist[t] = 0;
  if (t == 0) { sB1 = -1; sB2 = 0; sCount = 0; }
  __syncthreads();
  #pragma unroll
  for (int r = 0; r < 19; ++r)
    if (kreg[r]) atomicAdd(&hist[(int)(kreg[r] >> 54)], 1);
  __syncthreads();
  for (int d = 1; d < 1024; d <<= 1) {            // suffix scan
    int vv = hist[t] + ((t + d < 1024) ? hist[t + d] : 0);
    __syncthreads();
    hist[t] = vv;
    __syncthreads();
  }
  if (hist[t] >= KK) atomicMax(&sB1, t);
  __syncthreads();
  const int b1 = sB1;
  if (t == 0 && b1 >= 0) sNeed = KK - ((b1 < 1023) ? hist[b1 + 1] : 0);
  __syncthreads();
  int b2 = 0;
  if (b1 >= 0) {
    hist[t] = 0;
    __syncthreads();
    #pragma unroll
    for (int r = 0; r < 19; ++r) {
      unsigned long long k = kreg[r];
      if (k && (int)(k >> 54) == b1) atomicAdd(&hist[(int)(k >> 44) & 1023], 1);
    }
    __syncthreads();
    for (int d = 1; d < 1024; d <<= 1) {
      int vv = hist[t] + ((t + d < 1024) ? hist[t + d] : 0);
      __syncthreads();
      hist[t] = vv;
      __syncthreads();
    }
    if (hist[t] >= sNeed) atomicMax(&sB2, t);
    __syncthreads();
    b2 = sB2;
  }
  #pragma unroll
  for (int r = 0; r < 19; ++r) {
    unsigned long long k = kreg[r];
    if (k) {
      int bin1 = (int)(k >> 54);
      if (bin1 > b1 || (bin1 == b1 && ((int)(k >> 44) & 1023) >= b2)) {
        int pos = atomicAdd(&sCount, 1);
        if (pos < SVN) surv[imgI*SVN + pos] = k;
      }
    }
  }
  __syncthreads();
  if (t == 0) svcnt[imgI] = (sCount < SVN) ? sCount : SVN;
}

// ---------------------------------------------------------------------------
// Rank-and-emit: 16 blocks/image x 64 thr. Each block stages all survivors in
// LDS; thread k ranks its key against all n (broadcast reads). rank r < 512
// -> write kpts/kidx[r]. Ranks unique (keys unique) -> deterministic.
// ---------------------------------------------------------------------------
__global__ __launch_bounds__(64) void rank_kernel(const unsigned long long* __restrict__ surv,
    const int* __restrict__ svcnt, float* __restrict__ kptsOut, int* __restrict__ kidx) {
  __shared__ unsigned long long sk[SVN];
  const int imgI = blockIdx.y, t = threadIdx.x;
  const int n = svcnt[imgI];
  for (int i = t; i < SVN; i += 64) sk[i] = (i < n) ? surv[imgI*SVN + i] : 0ull;
  __syncthreads();
  const int k = blockIdx.x*64 + t;
  if (k < n) {
    unsigned long long key = sk[k];
    int r = 0;
    for (int m = 0; m < n; ++m) r += (sk[m] > key) ? 1 : 0;
    if (r < KK) {
      int id = (int)(~(unsigned int)(key & 0xFFFFFFFFull));
      kptsOut[imgI*2*KK + 2*r]     = (float)(id / WW);
      kptsOut[imgI*2*KK + 2*r + 1] = (float)(id % WW);
      kidx[imgI*KK + r] = id;
    }
  } else if (k >= n && k < KK) {     // only when n < 512: fill invalid slots
    kptsOut[imgI*2*KK + 2*k]     = -1.f;
    kptsOut[imgI*2*KK + 2*k + 1] = -1.f;
    kidx[imgI*KK + k] = -1;
  }
}

// ---------------------------------------------------------------------------
// Per-keypoint BAD descriptor (edge-clamped gathers on smooth) + L2 norm + s
// ---------------------------------------------------------------------------
__global__ __launch_bounds__(256) void desc_kernel(const float* __restrict__ smooth,
    const int* __restrict__ kidx, float* __restrict__ desc, float* __restrict__ sbuf) {
  __shared__ float wsum[4];
  const int k = blockIdx.x, imgI = blockIdx.y;
  const int j = threadIdx.x;
  const int id = kidx[imgI*KK + k];
  float val = 0.f;
  if (id >= 0) {
    int y = id / WW, x = id % WW;
    int o0 = OFFS.v[4*j], o1 = OFFS.v[4*j+1], o2 = OFFS.v[4*j+2], o3 = OFFS.v[4*j+3];
    const float* sm = smooth + imgI*HW;
    int ya = min(max(y+o0, 0), HH-1), xa = min(max(x+o1, 0), WW-1);
    int yb = min(max(y+o2, 0), HH-1), xb = min(max(x+o3, 0), WW-1);
    val = sm[ya*WW + xa] - sm[yb*WW + xb];
  }
  float ss = val*val;
  for (int off = 32; off; off >>= 1) ss += __shfl_down(ss, off);
  if ((j & 63) == 0) wsum[j >> 6] = ss;
  __syncthreads();
  if (j == 0) wsum[0] = wsum[0] + wsum[1] + wsum[2] + wsum[3];
  __syncthreads();
  float tot = wsum[0];
  float inv = 1.f / (sqrtf(tot) + 1e-12f);
  desc[((size_t)imgI*KK + k)*DD + j] = val * inv;
  if (j == 0) sbuf[imgI*KK + k] = tot * inv * inv;
}

// ---------------------------------------------------------------------------
// Z (dense 512x512, stride 512) = -sqrt(clip(s1+s2-2*d1.d2, 1e-12)).
// Dustbins are NOT stored (handled as constant 1.0 in sinkhorn).
// ---------------------------------------------------------------------------
__global__ __launch_bounds__(256) void zbuild_kernel(const float* __restrict__ desc,
    const float* __restrict__ sbuf, float* __restrict__ Z) {
  __shared__ float sA[16][260], sB[16][260];
  const int ty = threadIdx.y, tx = threadIdx.x;
  const int i0 = blockIdx.y*16, j0 = blockIdx.x*16;
  const int lt = ty*16 + tx;
  for (int p = lt; p < 16*DD; p += 256) {
    int r = p / DD, c = p % DD;
    sA[r][c] = desc[((size_t)0*KK + i0 + r)*DD + c];
    sB[r][c] = desc[((size_t)1*KK + j0 + r)*DD + c];
  }
  __syncthreads();
  const int i = i0 + ty, j = j0 + tx;
  const float4* pa = (const float4*)&sA[ty][0];
  const float4* pb = (const float4*)&sB[tx][0];
  float acc = 0.f;
  for (int c4 = 0; c4 < DD/4; ++c4) {
    float4 a = pa[c4], b = pb[c4];
    acc += a.x*b.x; acc += a.y*b.y; acc += a.z*b.z; acc += a.w*b.w;
  }
  float d2 = sbuf[0*KK + i] + sbuf[KK + j] - 2.f*acc;
  Z[(size_t)i*KK + j] = -sqrtf(fmaxf(d2, 1e-12f));
}

// ---------------------------------------------------------------------------
// Split-phase Sinkhorn step (dense Z, constant dustbins, float4 loads).
// mode 0: v=0; row pass. mode 1: v-update; row pass. mode 2: v-update; probs.
// ---------------------------------------------------------------------------
__global__ __launch_bounds__(1024) void sink_step_kernel(const float* __restrict__ Z,
    const float* __restrict__ PcolIn, float* __restrict__ PcolOut,
    const float* __restrict__ vIn, float* __restrict__ vOut,
    float* __restrict__ uBuf, float* __restrict__ probs, int mode) {
  __shared__ float v[KP1];
  __shared__ float pcolw[16][KP1];
  const int t = threadIdx.x, b = blockIdx.x;
  const int widx = t >> 6, lane = t & 63;
  const int gw = b*16 + widx;   // 0..511
  if (mode == 0) {
    for (int j = t; j < KP1; j += 1024) v[j] = 0.f;
  } else {
    for (int j = t; j < KP1; j += 1024) {
      float s = 0.f;
      #pragma unroll
      for (int w = 0; w < SB; ++w) s += PcolIn[w*KP1 + j];
      float lognu = (j < KK) ? NORM_F : (LOGK_F + NORM_F);
      v[j] = lognu + vIn[j] - logf(s);
    }
  }
  __syncthreads();
  const int j0 = lane*8;
  const float4 va = *(const float4*)&v[j0];
  const float4 vb = *(const float4*)&v[j0+4];
  const float vv[8] = {va.x, va.y, va.z, va.w, vb.x, vb.y, vb.z, vb.w};
  const int nrows = (gw == 511) ? 2 : 1;
  if (mode == 2) {
    for (int rr = 0; rr < nrows; ++rr) {
      const int r = rr ? 512 : gw;
      float* pr = probs + (size_t)r*KP1;
      const float ur = uBuf[r];
      float zv[8];
      if (r < 512) {
        float4 z0 = *(const float4*)&Z[(size_t)r*KK + j0];
        float4 z1 = *(const float4*)&Z[(size_t)r*KK + j0 + 4];
        zv[0]=z0.x; zv[1]=z0.y; zv[2]=z0.z; zv[3]=z0.w;
        zv[4]=z1.x; zv[5]=z1.y; zv[6]=z1.z; zv[7]=z1.w;
      } else {
        #pragma unroll
        for (int q = 0; q < 8; ++q) zv[q] = 1.0f;
      }
      #pragma unroll
      for (int q = 0; q < 8; ++q) pr[j0+q] = expf(zv[q] + ur + vv[q] - NORM_F);
      if (lane == 0) pr[512] = expf(1.0f + ur + v[512] - NORM_F);
    }
    return;
  }
  float pacc[8]; float pacc8 = 0.f;
  #pragma unroll
  for (int q = 0; q < 8; ++q) pacc[q] = 0.f;
  for (int rr = 0; rr < nrows; ++rr) {
    const int r = rr ? 512 : gw;
    float zv[8];
    if (r < 512) {
      float4 z0 = *(const float4*)&Z[(size_t)r*KK + j0];
      float4 z1 = *(const float4*)&Z[(size_t)r*KK + j0 + 4];
      zv[0]=z0.x; zv[1]=z0.y; zv[2]=z0.z; zv[3]=z0.w;
      zv[4]=z1.x; zv[5]=z1.y; zv[6]=z1.z; zv[7]=z1.w;
    } else {
      #pragma unroll
      for (int q = 0; q < 8; ++q) zv[q] = 1.0f;
    }
    float tv[8]; float S = 0.f;
    #pragma unroll
    for (int q = 0; q < 8; ++q) { tv[q] = expf(zv[q] + vv[q]); S += tv[q]; }
    float t8 = 0.f;
    if (lane == 0) { t8 = expf(1.0f + v[512]); S += t8; }
    #pragma unroll
    for (int off = 32; off; off >>= 1) S += __shfl_xor(S, off);
    float mu = (r < 512) ? MU0 : MU1;
    float eu = mu / S;
    if (lane == 0) uBuf[r] = logf(eu);
    #pragma unroll
    for (int q = 0; q < 8; ++q) pacc[q] += tv[q] * eu;
    pacc8 += t8 * eu;
  }
  #pragma unroll
  for (int q = 0; q < 8; ++q) pcolw[widx][j0+q] = pacc[q];
  if (lane == 0) pcolw[widx][512] = pacc8;
  __syncthreads();
  float* pc = PcolOut + (size_t)b*KP1;
  for (int j = t; j < KP1; j += 1024) {
    float s = 0.f;
    #pragma unroll
    for (int w = 0; w < 16; ++w) s += pcolw[w][j];
    pc[j] = s;
  }
  if (b == 0) {
    for (int j = t; j < KP1; j += 1024) vOut[j] = v[j];
  }
}

extern "C" void kernel_launch(void* const* d_in, const int* in_sizes, int n_in,
                              void* d_out, int out_size, void* d_ws, size_t ws_size,
                              hipStream_t stream) {
  const float* img1 = (const float*)d_in[0];
  const float* img2 = (const float*)d_in[1];
  float* out = (float*)d_out;
  char* ws = (char*)d_ws;

  unsigned long long* surv = (unsigned long long*)(ws + OFF_SURV);
  float* smooth = (float*)(ws + OFF_SMOOTH);
  unsigned long long* cand = (unsigned long long*)(ws + OFF_CAND);
  int*   kidx   = (int*)  (ws + OFF_KIDX);
  float* desc   = (float*)(ws + OFF_DESC);
  float* sbuf   = (float*)(ws + OFF_SBUF);
  float* Z      = (float*)(ws + OFF_Z);
  float* pcA    = (float*)(ws + OFF_PCA);
  float* pcB    = (float*)(ws + OFF_PCB);
  float* vA     = (float*)(ws + OFF_VA);
  float* vB     = (float*)(ws + OFF_VB);
  float* uBuf   = (float*)(ws + OFF_U);
  int*   svcnt  = (int*)  (ws + OFF_SVCNT);
  float* probsOut = out + 2*KK*2;

  detnms_kernel<<<dim3(NBX, NBY, 2), dim3(16, 16), 0, stream>>>(img1, img2, smooth, cand);
  select2a_kernel<<<2, 1024, 0, stream>>>(cand, surv, svcnt);
  rank_kernel<<<dim3(16, 2), 64, 0, stream>>>(surv, svcnt, out, kidx);
  desc_kernel<<<dim3(KK, 2), 256, 0, stream>>>(smooth, kidx, desc, sbuf);
  zbuild_kernel<<<dim3(32, 32), dim3(16, 16), 0, stream>>>(desc, sbuf, Z);

  sink_step_kernel<<<SB, 1024, 0, stream>>>(Z, pcB, pcA, vB, vA, uBuf, probsOut, 0);
  int ping = 0;
  for (int it = 1; it < 20; ++it) {
    float* pin  = ping ? pcB : pcA;
    float* pout = ping ? pcA : pcB;
    float* vin  = ping ? vB  : vA;
    float* vout = ping ? vA  : vB;
    sink_step_kernel<<<SB, 1024, 0, stream>>>(Z, pin, pout, vin, vout, uBuf, probsOut, 1);
    ping ^= 1;
  }
  {
    float* pin = ping ? pcB : pcA;
    float* vin = ping ? vB  : vA;
    sink_step_kernel<<<SB, 1024, 0, stream>>>(Z, pin, pcA, vin, vA, uBuf, probsOut, 2);
  }
}